// Round 1
// baseline (2137.158 us; speedup 1.0000x reference)
//
#include <hip/hip_runtime.h>
#include <math.h>

#define N_NODES 40000
#define N_EDGES 640000
#define ETOT    (N_EDGES + N_NODES)
#define DINC    512            // DIN == H*C
#define NHEAD   4
#define CHD     128
#define BN_EPS  1e-5f

static __device__ __forceinline__ float lrelu(float x) { return x > 0.f ? x : 0.2f * x; }

// ---------------- CSR build ----------------
__global__ void k_degree(const int* __restrict__ ei, int* __restrict__ cnt) {
    int e = blockIdx.x * 256 + threadIdx.x;
    if (e < ETOT) {
        int dst = (e < N_EDGES) ? ei[N_EDGES + e] : (e - N_EDGES);
        atomicAdd(&cnt[dst], 1);
    }
}

__global__ __launch_bounds__(1024) void k_scan(const int* __restrict__ deg, int* __restrict__ rowptr) {
    __shared__ int buf[1024];
    __shared__ int carry;
    int tid = threadIdx.x;
    if (tid == 0) carry = 0;
    __syncthreads();
    for (int base = 0; base < N_NODES; base += 1024) {
        int i = base + tid;
        int v = (i < N_NODES) ? deg[i] : 0;
        buf[tid] = v;
        __syncthreads();
        for (int off = 1; off < 1024; off <<= 1) {
            int t = (tid >= off) ? buf[tid - off] : 0;
            __syncthreads();
            buf[tid] += t;
            __syncthreads();
        }
        if (i < N_NODES) rowptr[i] = carry + buf[tid] - v;   // exclusive
        __syncthreads();
        if (tid == 1023) carry += buf[1023];
        __syncthreads();
    }
    if (tid == 0) rowptr[N_NODES] = carry;
}

__global__ void k_fill(const int* __restrict__ ei, const int* __restrict__ rowptr,
                       int* __restrict__ cnt, int* __restrict__ csr_src) {
    int e = blockIdx.x * 256 + threadIdx.x;
    if (e < ETOT) {
        int src, dst;
        if (e < N_EDGES) { src = ei[e]; dst = ei[N_EDGES + e]; }
        else             { src = e - N_EDGES; dst = src; }
        int pos = rowptr[dst] + atomicAdd(&cnt[dst], 1);
        csr_src[pos] = src;
    }
}

// ---------------- f32 tiled GEMM: C[M,Nn] = A[M,K] @ B[K,Nn] ----------------
#define GBM 64
#define GBN 64
#define GBK 16
__global__ __launch_bounds__(256) void k_gemm(const float* __restrict__ A,
                                              const float* __restrict__ B,
                                              float* __restrict__ C,
                                              int M, int Nn, int K) {
    __shared__ float As[GBK][GBM + 4];
    __shared__ float Bs[GBK][GBN + 4];
    const int tid = threadIdx.x;
    const int tx = tid & 15;
    const int ty = tid >> 4;
    const int mblocks = M / GBM;
    const int bm = (blockIdx.x % mblocks) * GBM;
    const int bn = (blockIdx.x / mblocks) * GBN;

    const int ar = tid >> 2;          // 0..63
    const int ac = (tid & 3) * 4;     // 0,4,8,12
    const int br = tid >> 4;          // 0..15
    const int bc = (tid & 15) * 4;    // 0..60

    float acc[4][4] = {};

    for (int k0 = 0; k0 < K; k0 += GBK) {
        float4 av = *(const float4*)(A + (size_t)(bm + ar) * K + k0 + ac);
        float4 bv = *(const float4*)(B + (size_t)(k0 + br) * Nn + bn + bc);
        __syncthreads();
        As[ac + 0][ar] = av.x;
        As[ac + 1][ar] = av.y;
        As[ac + 2][ar] = av.z;
        As[ac + 3][ar] = av.w;
        *(float4*)&Bs[br][bc] = bv;
        __syncthreads();
#pragma unroll
        for (int k = 0; k < GBK; ++k) {
            float4 a = *(const float4*)&As[k][ty * 4];
            float4 b = *(const float4*)&Bs[k][tx * 4];
            acc[0][0] += a.x * b.x; acc[0][1] += a.x * b.y; acc[0][2] += a.x * b.z; acc[0][3] += a.x * b.w;
            acc[1][0] += a.y * b.x; acc[1][1] += a.y * b.y; acc[1][2] += a.y * b.z; acc[1][3] += a.y * b.w;
            acc[2][0] += a.z * b.x; acc[2][1] += a.z * b.y; acc[2][2] += a.z * b.z; acc[2][3] += a.z * b.w;
            acc[3][0] += a.w * b.x; acc[3][1] += a.w * b.y; acc[3][2] += a.w * b.z; acc[3][3] += a.w * b.w;
        }
    }
#pragma unroll
    for (int i = 0; i < 4; ++i) {
        float4 o = make_float4(acc[i][0], acc[i][1], acc[i][2], acc[i][3]);
        *(float4*)(C + (size_t)(bm + ty * 4 + i) * Nn + bn + tx * 4) = o;
    }
}

// ---------------- es/ed per (node, head) ----------------
__global__ __launch_bounds__(256) void k_esed(const float* __restrict__ h,
                                              const float* __restrict__ as_,
                                              const float* __restrict__ ad_,
                                              float* __restrict__ es,
                                              float* __restrict__ ed) {
    int n = blockIdx.x;
    int hd = threadIdx.x >> 6;
    int lane = threadIdx.x & 63;
    const float* hp = h + (size_t)n * DINC + hd * CHD;
    float h0 = hp[lane], h1 = hp[lane + 64];
    const float* ap = as_ + hd * CHD;
    const float* dp = ad_ + hd * CHD;
    float s = h0 * ap[lane] + h1 * ap[lane + 64];
    float d = h0 * dp[lane] + h1 * dp[lane + 64];
#pragma unroll
    for (int off = 32; off; off >>= 1) {
        s += __shfl_xor(s, off);
        d += __shfl_xor(d, off);
    }
    if (lane == 0) { es[n * NHEAD + hd] = s; ed[n * NHEAD + hd] = d; }
}

// ---------------- per-node edge softmax + aggregate (block per node) ----------------
#define AGG_CHUNK 64
__global__ __launch_bounds__(256) void k_agg(const float* __restrict__ h,
                                             const float4* __restrict__ es4,
                                             const float4* __restrict__ ed4,
                                             const int* __restrict__ rowptr,
                                             const int* __restrict__ csr_src,
                                             float* __restrict__ aggv) {
    const int n = blockIdx.x;
    const int tid = threadIdx.x;
    const int lane = tid & 63, wv = tid >> 6;
    const int start = rowptr[n], end = rowptr[n + 1];
    const float4 edn = ed4[n];

    __shared__ float red[4][NHEAD];

    // pass 1: per-head max
    float mx[NHEAD] = {-1e30f, -1e30f, -1e30f, -1e30f};
    for (int j = start + tid; j < end; j += 256) {
        int s = csr_src[j];
        float4 e = es4[s];
        mx[0] = fmaxf(mx[0], lrelu(e.x + edn.x));
        mx[1] = fmaxf(mx[1], lrelu(e.y + edn.y));
        mx[2] = fmaxf(mx[2], lrelu(e.z + edn.z));
        mx[3] = fmaxf(mx[3], lrelu(e.w + edn.w));
    }
#pragma unroll
    for (int off = 32; off; off >>= 1)
#pragma unroll
        for (int q = 0; q < NHEAD; ++q) mx[q] = fmaxf(mx[q], __shfl_xor(mx[q], off));
    if (lane == 0) { red[wv][0] = mx[0]; red[wv][1] = mx[1]; red[wv][2] = mx[2]; red[wv][3] = mx[3]; }
    __syncthreads();
    float m[NHEAD];
#pragma unroll
    for (int q = 0; q < NHEAD; ++q)
        m[q] = fmaxf(fmaxf(red[0][q], red[1][q]), fmaxf(red[2][q], red[3][q]));
    __syncthreads();

    // pass 2: per-head sum of exp
    float sm[NHEAD] = {0.f, 0.f, 0.f, 0.f};
    for (int j = start + tid; j < end; j += 256) {
        int s = csr_src[j];
        float4 e = es4[s];
        sm[0] += expf(lrelu(e.x + edn.x) - m[0]);
        sm[1] += expf(lrelu(e.y + edn.y) - m[1]);
        sm[2] += expf(lrelu(e.z + edn.z) - m[2]);
        sm[3] += expf(lrelu(e.w + edn.w) - m[3]);
    }
#pragma unroll
    for (int off = 32; off; off >>= 1)
#pragma unroll
        for (int q = 0; q < NHEAD; ++q) sm[q] += __shfl_xor(sm[q], off);
    if (lane == 0) { red[wv][0] = sm[0]; red[wv][1] = sm[1]; red[wv][2] = sm[2]; red[wv][3] = sm[3]; }
    __syncthreads();
    float inv[NHEAD];
#pragma unroll
    for (int q = 0; q < NHEAD; ++q)
        inv[q] = 1.f / (red[0][q] + red[1][q] + red[2][q] + red[3][q] + 1e-16f);
    __syncthreads();

    // pass 3: weighted aggregation, chunked w into LDS
    __shared__ float s_w[AGG_CHUNK][NHEAD];
    __shared__ int s_src[AGG_CHUNK];
    const int c0 = tid * 2;        // channels c0, c0+1 (same head)
    const int hd = tid >> 6;       // head of channel 2*tid
    float2 acc = make_float2(0.f, 0.f);
    for (int base = start; base < end; base += AGG_CHUNK) {
        int cnt = min(AGG_CHUNK, end - base);
        if (tid < cnt) {
            int s = csr_src[base + tid];
            s_src[tid] = s;
            float4 e = es4[s];
            s_w[tid][0] = expf(lrelu(e.x + edn.x) - m[0]) * inv[0];
            s_w[tid][1] = expf(lrelu(e.y + edn.y) - m[1]) * inv[1];
            s_w[tid][2] = expf(lrelu(e.z + edn.z) - m[2]) * inv[2];
            s_w[tid][3] = expf(lrelu(e.w + edn.w) - m[3]) * inv[3];
        }
        __syncthreads();
        for (int i = 0; i < cnt; ++i) {
            int s = s_src[i];
            float wgt = s_w[i][hd];
            float2 hv = *(const float2*)(h + (size_t)s * DINC + c0);
            acc.x += wgt * hv.x;
            acc.y += wgt * hv.y;
        }
        __syncthreads();
    }
    *(float2*)(aggv + (size_t)n * DINC + c0) = acc;
}

// ---------------- BatchNorm ----------------
__global__ __launch_bounds__(256) void k_bn_stats(const float* __restrict__ a, float* __restrict__ stats) {
    int tid = threadIdx.x;
    int row0 = blockIdx.x * 64;
    int c0 = tid, c1 = tid + 256;
    float s0 = 0, q0 = 0, s1 = 0, q1 = 0;
    for (int r = row0; r < row0 + 64; ++r) {
        float v0 = a[(size_t)r * DINC + c0];
        float v1 = a[(size_t)r * DINC + c1];
        s0 += v0; q0 += v0 * v0;
        s1 += v1; q1 += v1 * v1;
    }
    atomicAdd(&stats[c0], s0);
    atomicAdd(&stats[c1], s1);
    atomicAdd(&stats[DINC + c0], q0);
    atomicAdd(&stats[DINC + c1], q1);
}

__global__ __launch_bounds__(512) void k_bn_fin(const float* __restrict__ stats,
                                                const float* __restrict__ g,
                                                const float* __restrict__ be,
                                                float* __restrict__ ab) {
    int c = threadIdx.x;
    float mu = stats[c] * (1.f / N_NODES);
    float var = stats[DINC + c] * (1.f / N_NODES) - mu * mu;
    float rstd = rsqrtf(var + BN_EPS);
    float A = g[c] * rstd;
    ab[c] = A;
    ab[DINC + c] = be[c] - mu * A;
}

__global__ __launch_bounds__(256) void k_bn_act(const float4* __restrict__ agg4,
                                                const float* __restrict__ ab,
                                                float4* __restrict__ cur4,
                                                int res) {
    size_t idx = (size_t)blockIdx.x * 256 + threadIdx.x;   // < N*128
    int c4 = ((int)(idx & 127)) * 4;
    float4 v = agg4[idx];
    float4 A = *(const float4*)(ab + c4);
    float4 B = *(const float4*)(ab + DINC + c4);
    float x0 = lrelu(v.x * A.x + B.x);
    float x1 = lrelu(v.y * A.y + B.y);
    float x2 = lrelu(v.z * A.z + B.z);
    float x3 = lrelu(v.w * A.w + B.w);
    if (res) {
        float4 r = cur4[idx];
        x0 += r.x; x1 += r.y; x2 += r.z; x3 += r.w;
    }
    cur4[idx] = make_float4(x0, x1, x2, x3);
}

// ---------------- epilogue ----------------
__global__ __launch_bounds__(256) void k_scores(const float* __restrict__ G,
                                                float* __restrict__ F,
                                                const float* __restrict__ bg1,
                                                const float* __restrict__ Wg2,
                                                const float* __restrict__ bg2,
                                                const float* __restrict__ bf1,
                                                float* __restrict__ scores) {
    int n = blockIdx.x * 4 + (threadIdx.x >> 6);
    int lane = threadIdx.x & 63;
    float acc = 0.f;
#pragma unroll
    for (int rep = 0; rep < 2; ++rep) {
        int j = lane + rep * 64;
        float t = tanhf(G[(size_t)n * 128 + j] + bg1[j]);
        acc += t * Wg2[j];
        float f = F[(size_t)n * 128 + j] + bf1[j];
        F[(size_t)n * 128 + j] = fmaxf(f, 0.f);
    }
#pragma unroll
    for (int off = 32; off; off >>= 1) acc += __shfl_xor(acc, off);
    if (lane == 0) scores[n] = acc + bg2[0];
}

__global__ __launch_bounds__(1024) void k_softmax(const float* __restrict__ scores, float* __restrict__ sm) {
    __shared__ float red[16];
    int tid = threadIdx.x, lane = tid & 63, wv = tid >> 6;
    float m = -1e30f;
    for (int i = tid; i < N_NODES; i += 1024) m = fmaxf(m, scores[i]);
#pragma unroll
    for (int off = 32; off; off >>= 1) m = fmaxf(m, __shfl_xor(m, off));
    if (lane == 0) red[wv] = m;
    __syncthreads();
    float mall = red[0];
    for (int i = 1; i < 16; ++i) mall = fmaxf(mall, red[i]);
    __syncthreads();
    float s = 0.f;
    for (int i = tid; i < N_NODES; i += 1024) s += expf(scores[i] - mall);
#pragma unroll
    for (int off = 32; off; off >>= 1) s += __shfl_xor(s, off);
    if (lane == 0) red[wv] = s;
    __syncthreads();
    if (tid == 0) {
        float tot = 0.f;
        for (int i = 0; i < 16; ++i) tot += red[i];
        sm[0] = mall; sm[1] = tot;
    }
}

__global__ __launch_bounds__(640) void k_vpool(const float* __restrict__ r1,
                                               const float* __restrict__ h,
                                               const float* __restrict__ scores,
                                               const float* __restrict__ sm,
                                               float* __restrict__ v,
                                               float* __restrict__ pooled) {
    int tid = threadIdx.x;
    int row0 = blockIdx.x * 64;
    float mall = sm[0];
    float invS = 1.f / sm[1];
    if (tid < 128) {
        float acc = 0.f;
        for (int r = row0; r < row0 + 64; ++r) {
            float w = expf(scores[r] - mall) * invS;
            acc += w * r1[(size_t)r * 128 + tid];
        }
        atomicAdd(&v[tid], acc);
    } else {
        int c = tid - 128;
        float acc = 0.f;
        for (int r = row0; r < row0 + 64; ++r) acc += h[(size_t)r * DINC + c];
        atomicAdd(&pooled[c], acc * (1.f / N_NODES));
    }
}

__global__ __launch_bounds__(128) void k_final(const float* __restrict__ v,
                                               const float* __restrict__ pooled,
                                               const float* __restrict__ Wf2,
                                               const float* __restrict__ bf2,
                                               const float* __restrict__ Wp,
                                               const float* __restrict__ bp,
                                               float* __restrict__ out) {
    __shared__ float sg[128];
    int o = threadIdx.x;
    float g = bf2[o];
    for (int k = 0; k < 128; ++k) g += v[k] * Wf2[k * 128 + o];
    sg[o] = g;
    __syncthreads();
    float acc = bp[o];
    for (int c = 0; c < 128; ++c) acc += sg[c] * Wp[c * 128 + o];
    for (int j = 0; j < 512; ++j) acc += pooled[j] * Wp[(128 + j) * 128 + o];
    out[o] = acc;
}

// ---------------- host launch ----------------
extern "C" void kernel_launch(void* const* d_in, const int* in_sizes, int n_in,
                              void* d_out, int out_size, void* d_ws, size_t ws_size,
                              hipStream_t stream) {
    const float* x  = (const float*)d_in[0];
    const int*   ei = (const int*)d_in[1];
    const float* Wg1 = (const float*)d_in[20];
    const float* bg1 = (const float*)d_in[21];
    const float* Wg2 = (const float*)d_in[22];
    const float* bg2 = (const float*)d_in[23];
    const float* Wf1 = (const float*)d_in[24];
    const float* bf1 = (const float*)d_in[25];
    const float* Wf2 = (const float*)d_in[26];
    const float* bf2 = (const float*)d_in[27];
    const float* Wp  = (const float*)d_in[28];
    const float* bp  = (const float*)d_in[29];
    float* out = (float*)d_out;

    char* base = (char*)d_ws;
    size_t off = 0;
    auto take = [&](size_t nbytes) -> char* {
        char* p = base + off;
        off += (nbytes + 255) & ~(size_t)255;
        return p;
    };
    float* cur   = (float*)take((size_t)N_NODES * DINC * 4);
    float* hbuf  = (float*)take((size_t)N_NODES * DINC * 4);
    float* agg   = (float*)take((size_t)N_NODES * DINC * 4);
    float* es    = (float*)take((size_t)N_NODES * NHEAD * 4);
    float* ed    = (float*)take((size_t)N_NODES * NHEAD * 4);
    int*   rowptr= (int*)take((size_t)(N_NODES + 1) * 4);
    int*   cnt   = (int*)take((size_t)N_NODES * 4);
    int*   csr   = (int*)take((size_t)ETOT * 4);
    float* stats = (float*)take(DINC * 2 * 4);
    float* ab    = (float*)take(DINC * 2 * 4);
    float* sm    = (float*)take(2 * 4);
    float* vbuf  = (float*)take(128 * 4);
    float* pooled= (float*)take(DINC * 4);
    // G/F reuse hbuf (free after layer 3)
    float* G = hbuf;
    float* F = hbuf + (size_t)N_NODES * 128;

    // CSR build
    hipMemsetAsync(cnt, 0, N_NODES * 4, stream);
    k_degree<<<(ETOT + 255) / 256, 256, 0, stream>>>(ei, cnt);
    k_scan<<<1, 1024, 0, stream>>>(cnt, rowptr);
    hipMemsetAsync(cnt, 0, N_NODES * 4, stream);
    k_fill<<<(ETOT + 255) / 256, 256, 0, stream>>>(ei, rowptr, cnt, csr);

    const float* in = x;
    for (int l = 0; l < 3; ++l) {
        const float* W   = (const float*)d_in[2 + l * 6 + 0];
        const float* as_ = (const float*)d_in[2 + l * 6 + 1];
        const float* ad_ = (const float*)d_in[2 + l * 6 + 2];
        const float* g   = (const float*)d_in[2 + l * 6 + 4];
        const float* be  = (const float*)d_in[2 + l * 6 + 5];

        k_gemm<<<(N_NODES / GBM) * (DINC / GBN), 256, 0, stream>>>(in, W, hbuf, N_NODES, DINC, DINC);
        k_esed<<<N_NODES, 256, 0, stream>>>(hbuf, as_, ad_, es, ed);
        k_agg<<<N_NODES, 256, 0, stream>>>(hbuf, (const float4*)es, (const float4*)ed, rowptr, csr, agg);
        hipMemsetAsync(stats, 0, DINC * 2 * 4, stream);
        k_bn_stats<<<N_NODES / 64, 256, 0, stream>>>(agg, stats);
        k_bn_fin<<<1, 512, 0, stream>>>(stats, g, be, ab);
        k_bn_act<<<(N_NODES * (DINC / 4)) / 256, 256, 0, stream>>>((const float4*)agg, ab, (float4*)cur, l > 0 ? 1 : 0);
        in = cur;
    }

    // epilogue projections
    k_gemm<<<(N_NODES / GBM) * (128 / GBN), 256, 0, stream>>>(cur, Wg1, G, N_NODES, 128, DINC);
    k_gemm<<<(N_NODES / GBM) * (128 / GBN), 256, 0, stream>>>(cur, Wf1, F, N_NODES, 128, DINC);

    float* scores = out + 128;
    k_scores<<<N_NODES / 4, 256, 0, stream>>>(G, F, bg1, Wg2, bg2, bf1, scores);
    k_softmax<<<1, 1024, 0, stream>>>(scores, sm);
    hipMemsetAsync(vbuf, 0, 128 * 4, stream);
    hipMemsetAsync(pooled, 0, DINC * 4, stream);
    k_vpool<<<N_NODES / 64, 640, 0, stream>>>(F, cur, scores, sm, vbuf, pooled);
    k_final<<<1, 128, 0, stream>>>(vbuf, pooled, Wf2, bf2, Wp, bp, out);
}

// Round 2
// 1059.358 us; speedup vs baseline: 2.0174x; 2.0174x over previous
//
#include <hip/hip_runtime.h>
#include <math.h>

#define N_NODES 40000
#define M_PAD   40064          // 313 * 128
#define N_EDGES 640000
#define ETOT    (N_EDGES + N_NODES)
#define DINC    512            // DIN == H*C
#define NHEAD   4
#define CHD     128
#define BN_EPS  1e-5f

typedef __attribute__((ext_vector_type(8))) short bf16x8;
typedef __attribute__((ext_vector_type(4))) float f32x4;

static __device__ __forceinline__ float lrelu(float x) { return x > 0.f ? x : 0.2f * x; }

static __device__ __forceinline__ unsigned short f2b(float f) {
    union { float f; unsigned int u; } v; v.f = f;
    unsigned int r = (v.u + 0x7fff + ((v.u >> 16) & 1)) >> 16;
    return (unsigned short)r;
}
static __device__ __forceinline__ float b2f(unsigned short b) {
    union { unsigned int u; float f; } v; v.u = ((unsigned int)b) << 16;
    return v.f;
}

#define GLDS16(g, l) __builtin_amdgcn_global_load_lds( \
    (__attribute__((address_space(1))) void*)(g),      \
    (__attribute__((address_space(3))) void*)(l), 16, 0, 0)

// ---------------- CSR build ----------------
__global__ void k_degree(const int* __restrict__ ei, int* __restrict__ cnt) {
    int e = blockIdx.x * 256 + threadIdx.x;
    if (e < ETOT) {
        int dst = (e < N_EDGES) ? ei[N_EDGES + e] : (e - N_EDGES);
        atomicAdd(&cnt[dst], 1);
    }
}

__global__ __launch_bounds__(1024) void k_scan(const int* __restrict__ deg, int* __restrict__ rowptr) {
    __shared__ int buf[1024];
    __shared__ int carry;
    int tid = threadIdx.x;
    if (tid == 0) carry = 0;
    __syncthreads();
    for (int base = 0; base < N_NODES; base += 1024) {
        int i = base + tid;
        int v = (i < N_NODES) ? deg[i] : 0;
        buf[tid] = v;
        __syncthreads();
        for (int off = 1; off < 1024; off <<= 1) {
            int t = (tid >= off) ? buf[tid - off] : 0;
            __syncthreads();
            buf[tid] += t;
            __syncthreads();
        }
        if (i < N_NODES) rowptr[i] = carry + buf[tid] - v;   // exclusive
        __syncthreads();
        if (tid == 1023) carry += buf[1023];
        __syncthreads();
    }
    if (tid == 0) rowptr[N_NODES] = carry;
}

__global__ void k_fill(const int* __restrict__ ei, const int* __restrict__ rowptr,
                       int* __restrict__ cnt, int* __restrict__ csr_src) {
    int e = blockIdx.x * 256 + threadIdx.x;
    if (e < ETOT) {
        int src, dst;
        if (e < N_EDGES) { src = ei[e]; dst = ei[N_EDGES + e]; }
        else             { src = e - N_EDGES; dst = src; }
        int pos = rowptr[dst] + atomicAdd(&cnt[dst], 1);
        csr_src[pos] = src;
    }
}

// ---------------- conversions ----------------
__global__ __launch_bounds__(256) void k_cvtx(const float4* __restrict__ xin, uint4* __restrict__ xb) {
    size_t i = (size_t)blockIdx.x * 256 + threadIdx.x;   // < N*512/8
    float4 a = xin[i * 2], b = xin[i * 2 + 1];
    uint4 o;
    o.x = (unsigned)f2b(a.x) | ((unsigned)f2b(a.y) << 16);
    o.y = (unsigned)f2b(a.z) | ((unsigned)f2b(a.w) << 16);
    o.z = (unsigned)f2b(b.x) | ((unsigned)f2b(b.y) << 16);
    o.w = (unsigned)f2b(b.z) | ((unsigned)f2b(b.w) << 16);
    xb[i] = o;
}

// W [K][Nn] f32 -> Wt [Nn][K] bf16
__global__ __launch_bounds__(256) void k_cvtw(const float* __restrict__ W, unsigned short* __restrict__ Wt,
                                              int K, int Nn) {
    int idx = blockIdx.x * 256 + threadIdx.x;
    int k = idx / Nn, n = idx % Nn;
    Wt[(size_t)n * K + k] = f2b(W[idx]);
}

// ---------------- bf16 MFMA GEMM: C[M,Nn] = A[M,K] @ Bt[Nn,K]^T ----------------
// 128x128 tile, BK=64, 4 waves (2x2 of 64x64), global_load_lds staging with
// XOR-swizzled source so swizzled ds_read_b128 fragment reads are conflict-light.
template<int CBF16>
__global__ __launch_bounds__(256) void k_gemm_mfma(const unsigned short* __restrict__ A,
                                                   const unsigned short* __restrict__ Bt,
                                                   void* __restrict__ Cout,
                                                   int Nn, int K, int nbn) {
    __shared__ alignas(16) unsigned short As[128 * 64];
    __shared__ alignas(16) unsigned short Bs[128 * 64];
    const int tid  = threadIdx.x;
    const int wv   = tid >> 6;
    const int lane = tid & 63;
    const int bm = (blockIdx.x / nbn) * 128;
    const int bn = (blockIdx.x % nbn) * 128;
    const int wm = (wv >> 1) * 64;
    const int wn = (wv & 1) * 64;

    // staging geometry: one GLDS16 per wave moves 8 rows x 64 cols (1KB)
    const int srow = lane >> 3;                       // row within 8-row group
    const int scol = (((lane & 7) ^ srow) * 8);       // pre-swizzled source k-offset
    const size_t a_base = (size_t)(bm + wv * 32 + srow) * K + scol;
    const size_t b_base = (size_t)(bn + wv * 32 + srow) * K + scol;

    f32x4 acc[4][4] = {};

    for (int k0 = 0; k0 < K; k0 += 64) {
#pragma unroll
        for (int q = 0; q < 4; ++q)
            GLDS16(A + a_base + (size_t)q * 8 * K + k0, &As[(wv * 32 + q * 8) * 64]);
#pragma unroll
        for (int q = 0; q < 4; ++q)
            GLDS16(Bt + b_base + (size_t)q * 8 * K + k0, &Bs[(wv * 32 + q * 8) * 64]);
        __syncthreads();

        const int r0 = lane & 15;
#pragma unroll
        for (int ks = 0; ks < 2; ++ks) {
            const int c = ks * 4 + (lane >> 4);       // k-chunk 0..7 (8 bf16 each)
            bf16x8 af[4], bfr[4];
#pragma unroll
            for (int i = 0; i < 4; ++i) {
                int row = wm + i * 16 + r0;
                af[i] = *(const bf16x8*)&As[row * 64 + ((c ^ (row & 7)) * 8)];
            }
#pragma unroll
            for (int j = 0; j < 4; ++j) {
                int row = wn + j * 16 + r0;
                bfr[j] = *(const bf16x8*)&Bs[row * 64 + ((c ^ (row & 7)) * 8)];
            }
#pragma unroll
            for (int i = 0; i < 4; ++i)
#pragma unroll
                for (int j = 0; j < 4; ++j)
                    acc[i][j] = __builtin_amdgcn_mfma_f32_16x16x32_bf16(af[i], bfr[j], acc[i][j], 0, 0, 0);
        }
        __syncthreads();
    }

    const int crow0 = bm + wm + (lane >> 4) * 4;
    const int ccol  = bn + wn + (lane & 15);
#pragma unroll
    for (int i = 0; i < 4; ++i)
#pragma unroll
        for (int j = 0; j < 4; ++j)
#pragma unroll
            for (int r = 0; r < 4; ++r) {
                size_t off = (size_t)(crow0 + i * 16 + r) * Nn + ccol + j * 16;
                if (CBF16) ((unsigned short*)Cout)[off] = f2b(acc[i][j][r]);
                else       ((float*)Cout)[off] = acc[i][j][r];
            }
}

// ---------------- es/ed per (node, head) ----------------
__global__ __launch_bounds__(256) void k_esed(const unsigned short* __restrict__ hb,
                                              const float* __restrict__ as_,
                                              const float* __restrict__ ad_,
                                              float* __restrict__ es,
                                              float* __restrict__ ed) {
    int n = blockIdx.x;
    int hd = threadIdx.x >> 6;
    int lane = threadIdx.x & 63;
    unsigned int hv = *(const unsigned int*)&hb[(size_t)n * DINC + hd * CHD + lane * 2];
    float h0 = b2f((unsigned short)(hv & 0xffff));
    float h1 = b2f((unsigned short)(hv >> 16));
    float2 a = *(const float2*)&as_[hd * CHD + lane * 2];
    float2 d = *(const float2*)&ad_[hd * CHD + lane * 2];
    float s = h0 * a.x + h1 * a.y;
    float dd = h0 * d.x + h1 * d.y;
#pragma unroll
    for (int off = 32; off; off >>= 1) {
        s += __shfl_xor(s, off);
        dd += __shfl_xor(dd, off);
    }
    if (lane == 0) { es[n * NHEAD + hd] = s; ed[n * NHEAD + hd] = dd; }
}

// ---------------- per-node edge softmax + aggregate ----------------
#define AGG_CHUNK 64
__global__ __launch_bounds__(256) void k_agg(const unsigned short* __restrict__ hb,
                                             const float4* __restrict__ es4,
                                             const float4* __restrict__ ed4,
                                             const int* __restrict__ rowptr,
                                             const int* __restrict__ csr_src,
                                             float* __restrict__ aggv) {
    const int n = blockIdx.x;
    const int tid = threadIdx.x;
    const int lane = tid & 63, wv = tid >> 6;
    const int start = rowptr[n], end = rowptr[n + 1];
    const float4 edn = ed4[n];

    __shared__ float red[4][NHEAD];

    // pass 1: per-head max
    float mx[NHEAD] = {-1e30f, -1e30f, -1e30f, -1e30f};
    for (int j = start + tid; j < end; j += 256) {
        int s = csr_src[j];
        float4 e = es4[s];
        mx[0] = fmaxf(mx[0], lrelu(e.x + edn.x));
        mx[1] = fmaxf(mx[1], lrelu(e.y + edn.y));
        mx[2] = fmaxf(mx[2], lrelu(e.z + edn.z));
        mx[3] = fmaxf(mx[3], lrelu(e.w + edn.w));
    }
#pragma unroll
    for (int off = 32; off; off >>= 1)
#pragma unroll
        for (int q = 0; q < NHEAD; ++q) mx[q] = fmaxf(mx[q], __shfl_xor(mx[q], off));
    if (lane == 0) { red[wv][0] = mx[0]; red[wv][1] = mx[1]; red[wv][2] = mx[2]; red[wv][3] = mx[3]; }
    __syncthreads();
    float m[NHEAD];
#pragma unroll
    for (int q = 0; q < NHEAD; ++q)
        m[q] = fmaxf(fmaxf(red[0][q], red[1][q]), fmaxf(red[2][q], red[3][q]));
    __syncthreads();

    // pass 2: per-head sum of exp
    float sm[NHEAD] = {0.f, 0.f, 0.f, 0.f};
    for (int j = start + tid; j < end; j += 256) {
        int s = csr_src[j];
        float4 e = es4[s];
        sm[0] += expf(lrelu(e.x + edn.x) - m[0]);
        sm[1] += expf(lrelu(e.y + edn.y) - m[1]);
        sm[2] += expf(lrelu(e.z + edn.z) - m[2]);
        sm[3] += expf(lrelu(e.w + edn.w) - m[3]);
    }
#pragma unroll
    for (int off = 32; off; off >>= 1)
#pragma unroll
        for (int q = 0; q < NHEAD; ++q) sm[q] += __shfl_xor(sm[q], off);
    if (lane == 0) { red[wv][0] = sm[0]; red[wv][1] = sm[1]; red[wv][2] = sm[2]; red[wv][3] = sm[3]; }
    __syncthreads();
    float inv[NHEAD];
#pragma unroll
    for (int q = 0; q < NHEAD; ++q)
        inv[q] = 1.f / (red[0][q] + red[1][q] + red[2][q] + red[3][q] + 1e-16f);
    __syncthreads();

    // pass 3: weighted aggregation, chunked w into LDS, bf16 h gather
    __shared__ float s_w[AGG_CHUNK][NHEAD];
    __shared__ int s_src[AGG_CHUNK];
    const int c0 = tid * 2;
    const int hd = tid >> 6;
    float2 acc = make_float2(0.f, 0.f);
    for (int base = start; base < end; base += AGG_CHUNK) {
        int cnt = min(AGG_CHUNK, end - base);
        if (tid < cnt) {
            int s = csr_src[base + tid];
            s_src[tid] = s;
            float4 e = es4[s];
            s_w[tid][0] = expf(lrelu(e.x + edn.x) - m[0]) * inv[0];
            s_w[tid][1] = expf(lrelu(e.y + edn.y) - m[1]) * inv[1];
            s_w[tid][2] = expf(lrelu(e.z + edn.z) - m[2]) * inv[2];
            s_w[tid][3] = expf(lrelu(e.w + edn.w) - m[3]) * inv[3];
        }
        __syncthreads();
        for (int i = 0; i < cnt; ++i) {
            int s = s_src[i];
            float wgt = s_w[i][hd];
            unsigned int hv = *(const unsigned int*)&hb[(size_t)s * DINC + c0];
            acc.x += wgt * b2f((unsigned short)(hv & 0xffff));
            acc.y += wgt * b2f((unsigned short)(hv >> 16));
        }
        __syncthreads();
    }
    *(float2*)(aggv + (size_t)n * DINC + c0) = acc;
}

// ---------------- BatchNorm ----------------
__global__ __launch_bounds__(256) void k_bn_stats(const float* __restrict__ a, float* __restrict__ stats) {
    int tid = threadIdx.x;
    int row0 = blockIdx.x * 64;
    int c0 = tid, c1 = tid + 256;
    float s0 = 0, q0 = 0, s1 = 0, q1 = 0;
    for (int r = row0; r < row0 + 64; ++r) {
        float v0 = a[(size_t)r * DINC + c0];
        float v1 = a[(size_t)r * DINC + c1];
        s0 += v0; q0 += v0 * v0;
        s1 += v1; q1 += v1 * v1;
    }
    atomicAdd(&stats[c0], s0);
    atomicAdd(&stats[c1], s1);
    atomicAdd(&stats[DINC + c0], q0);
    atomicAdd(&stats[DINC + c1], q1);
}

__global__ __launch_bounds__(512) void k_bn_fin(const float* __restrict__ stats,
                                                const float* __restrict__ g,
                                                const float* __restrict__ be,
                                                float* __restrict__ ab) {
    int c = threadIdx.x;
    float mu = stats[c] * (1.f / N_NODES);
    float var = stats[DINC + c] * (1.f / N_NODES) - mu * mu;
    float rstd = rsqrtf(var + BN_EPS);
    float A = g[c] * rstd;
    ab[c] = A;
    ab[DINC + c] = be[c] - mu * A;
}

__global__ __launch_bounds__(256) void k_bn_act(const float4* __restrict__ agg4,
                                                const float* __restrict__ ab,
                                                unsigned short* __restrict__ curb,
                                                int res) {
    size_t idx = (size_t)blockIdx.x * 256 + threadIdx.x;   // < N*128
    int c4 = ((int)(idx & 127)) * 4;
    float4 v = agg4[idx];
    float4 A = *(const float4*)(ab + c4);
    float4 B = *(const float4*)(ab + DINC + c4);
    float x0 = lrelu(v.x * A.x + B.x);
    float x1 = lrelu(v.y * A.y + B.y);
    float x2 = lrelu(v.z * A.z + B.z);
    float x3 = lrelu(v.w * A.w + B.w);
    if (res) {
        ushort4 r = *(const ushort4*)&curb[idx * 4];
        x0 += b2f(r.x); x1 += b2f(r.y); x2 += b2f(r.z); x3 += b2f(r.w);
    }
    ushort4 o;
    o.x = f2b(x0); o.y = f2b(x1); o.z = f2b(x2); o.w = f2b(x3);
    *(ushort4*)&curb[idx * 4] = o;
}

// ---------------- epilogue ----------------
__global__ __launch_bounds__(256) void k_scores(const float* __restrict__ G,
                                                float* __restrict__ F,
                                                const float* __restrict__ bg1,
                                                const float* __restrict__ Wg2,
                                                const float* __restrict__ bg2,
                                                const float* __restrict__ bf1,
                                                float* __restrict__ scores) {
    int n = blockIdx.x * 4 + (threadIdx.x >> 6);
    int lane = threadIdx.x & 63;
    float acc = 0.f;
#pragma unroll
    for (int rep = 0; rep < 2; ++rep) {
        int j = lane + rep * 64;
        float t = tanhf(G[(size_t)n * 128 + j] + bg1[j]);
        acc += t * Wg2[j];
        float f = F[(size_t)n * 128 + j] + bf1[j];
        F[(size_t)n * 128 + j] = fmaxf(f, 0.f);
    }
#pragma unroll
    for (int off = 32; off; off >>= 1) acc += __shfl_xor(acc, off);
    if (lane == 0) scores[n] = acc + bg2[0];
}

__global__ __launch_bounds__(1024) void k_softmax(const float* __restrict__ scores, float* __restrict__ sm) {
    __shared__ float red[16];
    int tid = threadIdx.x, lane = tid & 63, wv = tid >> 6;
    float m = -1e30f;
    for (int i = tid; i < N_NODES; i += 1024) m = fmaxf(m, scores[i]);
#pragma unroll
    for (int off = 32; off; off >>= 1) m = fmaxf(m, __shfl_xor(m, off));
    if (lane == 0) red[wv] = m;
    __syncthreads();
    float mall = red[0];
    for (int i = 1; i < 16; ++i) mall = fmaxf(mall, red[i]);
    __syncthreads();
    float s = 0.f;
    for (int i = tid; i < N_NODES; i += 1024) s += expf(scores[i] - mall);
#pragma unroll
    for (int off = 32; off; off >>= 1) s += __shfl_xor(s, off);
    if (lane == 0) red[wv] = s;
    __syncthreads();
    if (tid == 0) {
        float tot = 0.f;
        for (int i = 0; i < 16; ++i) tot += red[i];
        sm[0] = mall; sm[1] = tot;
    }
}

__global__ __launch_bounds__(640) void k_vpool(const float* __restrict__ r1,
                                               const unsigned short* __restrict__ hb,
                                               const float* __restrict__ scores,
                                               const float* __restrict__ sm,
                                               float* __restrict__ v,
                                               float* __restrict__ pooled) {
    int tid = threadIdx.x;
    int row0 = blockIdx.x * 64;
    float mall = sm[0];
    float invS = 1.f / sm[1];
    if (tid < 128) {
        float acc = 0.f;
        for (int r = row0; r < row0 + 64; ++r) {
            float w = expf(scores[r] - mall) * invS;
            acc += w * r1[(size_t)r * 128 + tid];
        }
        atomicAdd(&v[tid], acc);
    } else {
        int c = tid - 128;
        float acc = 0.f;
        for (int r = row0; r < row0 + 64; ++r) acc += b2f(hb[(size_t)r * DINC + c]);
        atomicAdd(&pooled[c], acc * (1.f / N_NODES));
    }
}

__global__ __launch_bounds__(128) void k_final(const float* __restrict__ v,
                                               const float* __restrict__ pooled,
                                               const float* __restrict__ Wf2,
                                               const float* __restrict__ bf2,
                                               const float* __restrict__ Wp,
                                               const float* __restrict__ bp,
                                               float* __restrict__ out) {
    __shared__ float sg[128];
    int o = threadIdx.x;
    float g = bf2[o];
    for (int k = 0; k < 128; ++k) g += v[k] * Wf2[k * 128 + o];
    sg[o] = g;
    __syncthreads();
    float acc = bp[o];
    for (int c = 0; c < 128; ++c) acc += sg[c] * Wp[c * 128 + o];
    for (int j = 0; j < 512; ++j) acc += pooled[j] * Wp[(128 + j) * 128 + o];
    out[o] = acc;
}

// ---------------- host launch ----------------
extern "C" void kernel_launch(void* const* d_in, const int* in_sizes, int n_in,
                              void* d_out, int out_size, void* d_ws, size_t ws_size,
                              hipStream_t stream) {
    const float* x  = (const float*)d_in[0];
    const int*   ei = (const int*)d_in[1];
    const float* Wg1 = (const float*)d_in[20];
    const float* bg1 = (const float*)d_in[21];
    const float* Wg2 = (const float*)d_in[22];
    const float* bg2 = (const float*)d_in[23];
    const float* Wf1 = (const float*)d_in[24];
    const float* bf1 = (const float*)d_in[25];
    const float* Wf2 = (const float*)d_in[26];
    const float* bf2 = (const float*)d_in[27];
    const float* Wp  = (const float*)d_in[28];
    const float* bp  = (const float*)d_in[29];
    float* out = (float*)d_out;

    char* base = (char*)d_ws;
    size_t off = 0;
    auto take = [&](size_t nbytes) -> char* {
        char* p = base + off;
        off += (nbytes + 255) & ~(size_t)255;
        return p;
    };
    unsigned short* hb   = (unsigned short*)take((size_t)M_PAD * DINC * 2);  // GEMM out (bf16 h)
    unsigned short* curb = (unsigned short*)take((size_t)M_PAD * DINC * 2);  // activations bf16
    unsigned short* xb   = (unsigned short*)take((size_t)M_PAD * DINC * 2);  // x bf16
    float* agg   = (float*)take((size_t)M_PAD * DINC * 4);                   // f32 agg / reused as G,F
    float* es    = (float*)take((size_t)N_NODES * NHEAD * 4);
    float* ed    = (float*)take((size_t)N_NODES * NHEAD * 4);
    int*   rowptr= (int*)take((size_t)(N_NODES + 1) * 4);
    int*   cnt   = (int*)take((size_t)N_NODES * 4);
    int*   csr   = (int*)take((size_t)ETOT * 4);
    float* stats = (float*)take(DINC * 2 * 4);
    float* ab    = (float*)take(DINC * 2 * 4);
    float* sm    = (float*)take(2 * 4);
    float* vbuf  = (float*)take(128 * 4);
    float* pooled= (float*)take(DINC * 4);
    unsigned short* Wt1  = (unsigned short*)take((size_t)DINC * DINC * 2);
    unsigned short* Wt2  = (unsigned short*)take((size_t)DINC * DINC * 2);
    unsigned short* Wt3  = (unsigned short*)take((size_t)DINC * DINC * 2);
    unsigned short* Wg1t = (unsigned short*)take((size_t)128 * DINC * 2);
    unsigned short* Wf1t = (unsigned short*)take((size_t)128 * DINC * 2);
    float* G = agg;                               // [M_PAD,128] f32
    float* F = agg + (size_t)M_PAD * 128;         // [M_PAD,128] f32

    // conversions
    k_cvtx<<<(N_NODES * DINC / 8) / 256, 256, 0, stream>>>((const float4*)x, (uint4*)xb);
    hipMemsetAsync(xb + (size_t)N_NODES * DINC, 0, (size_t)(M_PAD - N_NODES) * DINC * 2, stream);
    hipMemsetAsync(curb + (size_t)N_NODES * DINC, 0, (size_t)(M_PAD - N_NODES) * DINC * 2, stream);
    k_cvtw<<<DINC * DINC / 256, 256, 0, stream>>>((const float*)d_in[2],  Wt1, DINC, DINC);
    k_cvtw<<<DINC * DINC / 256, 256, 0, stream>>>((const float*)d_in[8],  Wt2, DINC, DINC);
    k_cvtw<<<DINC * DINC / 256, 256, 0, stream>>>((const float*)d_in[14], Wt3, DINC, DINC);
    k_cvtw<<<DINC * 128 / 256, 256, 0, stream>>>(Wg1, Wg1t, DINC, 128);
    k_cvtw<<<DINC * 128 / 256, 256, 0, stream>>>(Wf1, Wf1t, DINC, 128);

    // CSR build
    hipMemsetAsync(cnt, 0, N_NODES * 4, stream);
    k_degree<<<(ETOT + 255) / 256, 256, 0, stream>>>(ei, cnt);
    k_scan<<<1, 1024, 0, stream>>>(cnt, rowptr);
    hipMemsetAsync(cnt, 0, N_NODES * 4, stream);
    k_fill<<<(ETOT + 255) / 256, 256, 0, stream>>>(ei, rowptr, cnt, csr);

    const unsigned short* Wts[3] = {Wt1, Wt2, Wt3};
    const unsigned short* in = xb;
    for (int l = 0; l < 3; ++l) {
        const float* as_ = (const float*)d_in[2 + l * 6 + 1];
        const float* ad_ = (const float*)d_in[2 + l * 6 + 2];
        const float* g   = (const float*)d_in[2 + l * 6 + 4];
        const float* be  = (const float*)d_in[2 + l * 6 + 5];

        k_gemm_mfma<1><<<(M_PAD / 128) * (DINC / 128), 256, 0, stream>>>(in, Wts[l], hb, DINC, DINC, DINC / 128);
        k_esed<<<N_NODES, 256, 0, stream>>>(hb, as_, ad_, es, ed);
        k_agg<<<N_NODES, 256, 0, stream>>>(hb, (const float4*)es, (const float4*)ed, rowptr, csr, agg);
        hipMemsetAsync(stats, 0, DINC * 2 * 4, stream);
        k_bn_stats<<<N_NODES / 64, 256, 0, stream>>>(agg, stats);
        k_bn_fin<<<1, 512, 0, stream>>>(stats, g, be, ab);
        k_bn_act<<<(N_NODES * (DINC / 4)) / 256, 256, 0, stream>>>((const float4*)agg, ab, curb, l > 0 ? 1 : 0);
        in = curb;
    }

    // epilogue projections (f32 out, reuse agg as G/F)
    k_gemm_mfma<0><<<(M_PAD / 128) * 1, 256, 0, stream>>>(curb, Wg1t, G, 128, DINC, 1);
    k_gemm_mfma<0><<<(M_PAD / 128) * 1, 256, 0, stream>>>(curb, Wf1t, F, 128, DINC, 1);

    float* scores = out + 128;
    k_scores<<<N_NODES / 4, 256, 0, stream>>>(G, F, bg1, Wg2, bg2, bf1, scores);
    k_softmax<<<1, 1024, 0, stream>>>(scores, sm);
    hipMemsetAsync(vbuf, 0, 128 * 4, stream);
    hipMemsetAsync(pooled, 0, DINC * 4, stream);
    k_vpool<<<N_NODES / 64, 640, 0, stream>>>(F, curb, scores, sm, vbuf, pooled);
    k_final<<<1, 128, 0, stream>>>(vbuf, pooled, Wf2, bf2, Wp, bp, out);
}

// Round 3
// 903.036 us; speedup vs baseline: 2.3666x; 1.1731x over previous
//
#include <hip/hip_runtime.h>
#include <math.h>

#define N_NODES 40000
#define M_PAD   40064          // 313 * 128
#define N_EDGES 640000
#define ETOT    (N_EDGES + N_NODES)
#define DINC    512            // DIN == H*C
#define NHEAD   4
#define CHD     128
#define BN_EPS  1e-5f

typedef __attribute__((ext_vector_type(8))) short bf16x8;
typedef __attribute__((ext_vector_type(4))) float f32x4;

static __device__ __forceinline__ float lrelu(float x) { return x > 0.f ? x : 0.2f * x; }

static __device__ __forceinline__ unsigned short f2b(float f) {
    union { float f; unsigned int u; } v; v.f = f;
    unsigned int r = (v.u + 0x7fff + ((v.u >> 16) & 1)) >> 16;
    return (unsigned short)r;
}
static __device__ __forceinline__ float b2f(unsigned short b) {
    union { unsigned int u; float f; } v; v.u = ((unsigned int)b) << 16;
    return v.f;
}
static __device__ __forceinline__ float lo16(unsigned int u) {
    union { unsigned int u; float f; } v; v.u = u << 16; return v.f;
}
static __device__ __forceinline__ float hi16(unsigned int u) {
    union { unsigned int u; float f; } v; v.u = u & 0xffff0000u; return v.f;
}

#define GLDS16(g, l) __builtin_amdgcn_global_load_lds( \
    (__attribute__((address_space(1))) void*)(g),      \
    (__attribute__((address_space(3))) void*)(l), 16, 0, 0)

// ---------------- CSR build ----------------
__global__ void k_degree(const int* __restrict__ ei, int* __restrict__ cnt) {
    int e = blockIdx.x * 256 + threadIdx.x;
    if (e < ETOT) {
        int dst = (e < N_EDGES) ? ei[N_EDGES + e] : (e - N_EDGES);
        atomicAdd(&cnt[dst], 1);
    }
}

// 3-phase scan: block sums -> scan of 625 sums -> per-block wave prefix
__global__ __launch_bounds__(64) void k_scan1(const int* __restrict__ deg, int* __restrict__ bsum) {
    int lane = threadIdx.x;
    int v = deg[blockIdx.x * 64 + lane];
#pragma unroll
    for (int off = 32; off; off >>= 1) v += __shfl_xor(v, off);
    if (lane == 0) bsum[blockIdx.x] = v;
}

__global__ __launch_bounds__(1024) void k_scan2(const int* __restrict__ bsum, int* __restrict__ bpref,
                                                int* __restrict__ rowptr) {
    __shared__ int buf[1024];
    int tid = threadIdx.x;
    int v = (tid < 625) ? bsum[tid] : 0;
    buf[tid] = v;
    __syncthreads();
    for (int off = 1; off < 1024; off <<= 1) {
        int t = (tid >= off) ? buf[tid - off] : 0;
        __syncthreads();
        buf[tid] += t;
        __syncthreads();
    }
    if (tid < 625) bpref[tid] = buf[tid] - v;   // exclusive
    if (tid == 0) rowptr[N_NODES] = ETOT;
}

__global__ __launch_bounds__(64) void k_scan3(const int* __restrict__ deg, const int* __restrict__ bpref,
                                              int* __restrict__ rowptr) {
    int lane = threadIdx.x;
    int i = blockIdx.x * 64 + lane;
    int v = deg[i];
    int inc = v;
#pragma unroll
    for (int off = 1; off < 64; off <<= 1) {
        int t = __shfl_up(inc, off);
        if (lane >= off) inc += t;
    }
    rowptr[i] = bpref[blockIdx.x] + inc - v;
}

__global__ void k_fill(const int* __restrict__ ei, const int* __restrict__ rowptr,
                       int* __restrict__ cnt, int* __restrict__ csr_src) {
    int e = blockIdx.x * 256 + threadIdx.x;
    if (e < ETOT) {
        int src, dst;
        if (e < N_EDGES) { src = ei[e]; dst = ei[N_EDGES + e]; }
        else             { src = e - N_EDGES; dst = src; }
        int pos = rowptr[dst] + atomicAdd(&cnt[dst], 1);
        csr_src[pos] = src;
    }
}

// ---------------- conversions ----------------
__global__ __launch_bounds__(256) void k_cvtx(const float4* __restrict__ xin, uint4* __restrict__ xb) {
    size_t i = (size_t)blockIdx.x * 256 + threadIdx.x;   // < N*512/8
    float4 a = xin[i * 2], b = xin[i * 2 + 1];
    uint4 o;
    o.x = (unsigned)f2b(a.x) | ((unsigned)f2b(a.y) << 16);
    o.y = (unsigned)f2b(a.z) | ((unsigned)f2b(a.w) << 16);
    o.z = (unsigned)f2b(b.x) | ((unsigned)f2b(b.y) << 16);
    o.w = (unsigned)f2b(b.z) | ((unsigned)f2b(b.w) << 16);
    xb[i] = o;
}

// W [K][Nn] f32 -> Wt [Nn][K] bf16
__global__ __launch_bounds__(256) void k_cvtw(const float* __restrict__ W, unsigned short* __restrict__ Wt,
                                              int K, int Nn) {
    int idx = blockIdx.x * 256 + threadIdx.x;
    int k = idx / Nn, n = idx % Nn;
    Wt[(size_t)n * K + k] = f2b(W[idx]);
}

// ---------------- bf16 MFMA GEMM: C[M,Nn] = A[M,K] @ Bt[Nn,K]^T ----------------
template<int CBF16>
__global__ __launch_bounds__(256) void k_gemm_mfma(const unsigned short* __restrict__ A,
                                                   const unsigned short* __restrict__ Bt,
                                                   void* __restrict__ Cout,
                                                   int Nn, int K, int nbn) {
    __shared__ alignas(16) unsigned short As[128 * 64];
    __shared__ alignas(16) unsigned short Bs[128 * 64];
    const int tid  = threadIdx.x;
    const int wv   = tid >> 6;
    const int lane = tid & 63;
    const int bm = (blockIdx.x / nbn) * 128;
    const int bn = (blockIdx.x % nbn) * 128;
    const int wm = (wv >> 1) * 64;
    const int wn = (wv & 1) * 64;

    const int srow = lane >> 3;
    const int scol = (((lane & 7) ^ srow) * 8);
    const size_t a_base = (size_t)(bm + wv * 32 + srow) * K + scol;
    const size_t b_base = (size_t)(bn + wv * 32 + srow) * K + scol;

    f32x4 acc[4][4] = {};

    for (int k0 = 0; k0 < K; k0 += 64) {
#pragma unroll
        for (int q = 0; q < 4; ++q)
            GLDS16(A + a_base + (size_t)q * 8 * K + k0, &As[(wv * 32 + q * 8) * 64]);
#pragma unroll
        for (int q = 0; q < 4; ++q)
            GLDS16(Bt + b_base + (size_t)q * 8 * K + k0, &Bs[(wv * 32 + q * 8) * 64]);
        __syncthreads();

        const int r0 = lane & 15;
#pragma unroll
        for (int ks = 0; ks < 2; ++ks) {
            const int c = ks * 4 + (lane >> 4);
            bf16x8 af[4], bfr[4];
#pragma unroll
            for (int i = 0; i < 4; ++i) {
                int row = wm + i * 16 + r0;
                af[i] = *(const bf16x8*)&As[row * 64 + ((c ^ (row & 7)) * 8)];
            }
#pragma unroll
            for (int j = 0; j < 4; ++j) {
                int row = wn + j * 16 + r0;
                bfr[j] = *(const bf16x8*)&Bs[row * 64 + ((c ^ (row & 7)) * 8)];
            }
#pragma unroll
            for (int i = 0; i < 4; ++i)
#pragma unroll
                for (int j = 0; j < 4; ++j)
                    acc[i][j] = __builtin_amdgcn_mfma_f32_16x16x32_bf16(af[i], bfr[j], acc[i][j], 0, 0, 0);
        }
        __syncthreads();
    }

    const int crow0 = bm + wm + (lane >> 4) * 4;
    const int ccol  = bn + wn + (lane & 15);
#pragma unroll
    for (int i = 0; i < 4; ++i)
#pragma unroll
        for (int j = 0; j < 4; ++j)
#pragma unroll
            for (int r = 0; r < 4; ++r) {
                size_t off = (size_t)(crow0 + i * 16 + r) * Nn + ccol + j * 16;
                if (CBF16) ((unsigned short*)Cout)[off] = f2b(acc[i][j][r]);
                else       ((float*)Cout)[off] = acc[i][j][r];
            }
}

// ---------------- es/ed: one wave per node, 16B/lane ----------------
__global__ __launch_bounds__(256) void k_esed(const unsigned short* __restrict__ hb,
                                              const float* __restrict__ as_,
                                              const float* __restrict__ ad_,
                                              float* __restrict__ es,
                                              float* __restrict__ ed) {
    int n = blockIdx.x * 4 + (threadIdx.x >> 6);
    int lane = threadIdx.x & 63;
    int head = lane >> 4;
    uint4 hv = *(const uint4*)&hb[(size_t)n * DINC + lane * 8];
    const float* ap = as_ + head * CHD + (lane & 15) * 8;
    const float* dp = ad_ + head * CHD + (lane & 15) * 8;
    float4 a0 = *(const float4*)ap, a1 = *(const float4*)(ap + 4);
    float4 d0 = *(const float4*)dp, d1 = *(const float4*)(dp + 4);
    float h0 = lo16(hv.x), h1 = hi16(hv.x), h2 = lo16(hv.y), h3 = hi16(hv.y);
    float h4 = lo16(hv.z), h5 = hi16(hv.z), h6 = lo16(hv.w), h7 = hi16(hv.w);
    float s = h0 * a0.x + h1 * a0.y + h2 * a0.z + h3 * a0.w
            + h4 * a1.x + h5 * a1.y + h6 * a1.z + h7 * a1.w;
    float d = h0 * d0.x + h1 * d0.y + h2 * d0.z + h3 * d0.w
            + h4 * d1.x + h5 * d1.y + h6 * d1.z + h7 * d1.w;
#pragma unroll
    for (int off = 8; off; off >>= 1) {
        s += __shfl_xor(s, off);
        d += __shfl_xor(d, off);
    }
    if ((lane & 15) == 0) { es[n * NHEAD + head] = s; ed[n * NHEAD + head] = d; }
}

// ---------------- per-edge softmax weights: one wave per node ----------------
__global__ __launch_bounds__(256) void k_wts(const float4* __restrict__ es4,
                                             const float4* __restrict__ ed4,
                                             const int* __restrict__ rowptr,
                                             const int* __restrict__ csr_src,
                                             float4* __restrict__ wbuf4,
                                             float4* __restrict__ inv4) {
    int n = blockIdx.x * 4 + (threadIdx.x >> 6);
    int lane = threadIdx.x & 63;
    int start = rowptr[n], end = rowptr[n + 1];
    float4 edn = ed4[n];
    float4 mx = make_float4(-1e30f, -1e30f, -1e30f, -1e30f);
    for (int j0 = start; j0 < end; j0 += 64) {
        int j = j0 + lane;
        if (j < end) {
            int s = csr_src[j];
            float4 e = es4[s];
            mx.x = fmaxf(mx.x, lrelu(e.x + edn.x));
            mx.y = fmaxf(mx.y, lrelu(e.y + edn.y));
            mx.z = fmaxf(mx.z, lrelu(e.z + edn.z));
            mx.w = fmaxf(mx.w, lrelu(e.w + edn.w));
        }
    }
#pragma unroll
    for (int off = 32; off; off >>= 1) {
        mx.x = fmaxf(mx.x, __shfl_xor(mx.x, off));
        mx.y = fmaxf(mx.y, __shfl_xor(mx.y, off));
        mx.z = fmaxf(mx.z, __shfl_xor(mx.z, off));
        mx.w = fmaxf(mx.w, __shfl_xor(mx.w, off));
    }
    float4 sum = make_float4(0.f, 0.f, 0.f, 0.f);
    for (int j0 = start; j0 < end; j0 += 64) {
        int j = j0 + lane;
        if (j < end) {
            int s = csr_src[j];
            float4 e = es4[s];
            float4 ex;
            ex.x = expf(lrelu(e.x + edn.x) - mx.x);
            ex.y = expf(lrelu(e.y + edn.y) - mx.y);
            ex.z = expf(lrelu(e.z + edn.z) - mx.z);
            ex.w = expf(lrelu(e.w + edn.w) - mx.w);
            wbuf4[j] = ex;
            sum.x += ex.x; sum.y += ex.y; sum.z += ex.z; sum.w += ex.w;
        }
    }
#pragma unroll
    for (int off = 32; off; off >>= 1) {
        sum.x += __shfl_xor(sum.x, off);
        sum.y += __shfl_xor(sum.y, off);
        sum.z += __shfl_xor(sum.z, off);
        sum.w += __shfl_xor(sum.w, off);
    }
    if (lane == 0) {
        float4 iv;
        iv.x = 1.f / (sum.x + 1e-16f);
        iv.y = 1.f / (sum.y + 1e-16f);
        iv.z = 1.f / (sum.z + 1e-16f);
        iv.w = 1.f / (sum.w + 1e-16f);
        inv4[n] = iv;
    }
}

// ---------------- aggregate: block per node, 4 groups x 64 lanes, 16B/lane ----------------
__global__ __launch_bounds__(256) void k_agg(const unsigned short* __restrict__ hb,
                                             const int* __restrict__ rowptr,
                                             const int* __restrict__ csr_src,
                                             const float* __restrict__ wbuf,
                                             const float* __restrict__ invp,
                                             unsigned short* __restrict__ aggb) {
    __shared__ float part[4][512];
    const int n = blockIdx.x;
    const int tid = threadIdx.x;
    const int grp = tid >> 6;
    const int lane = tid & 63;
    const int head = lane >> 4;
    const int start = rowptr[n], end = rowptr[n + 1];

    float acc[8] = {};
    int j = start + grp;
    int s_n = 0; float w_n = 0.f;
    if (j < end) { s_n = csr_src[j]; w_n = wbuf[j * 4 + head]; }
    while (j < end) {
        int s = s_n; float w = w_n;
        int j2 = j + 4;
        if (j2 < end) { s_n = csr_src[j2]; w_n = wbuf[j2 * 4 + head]; }
        uint4 hv = *(const uint4*)&hb[(size_t)s * DINC + lane * 8];
        acc[0] += w * lo16(hv.x); acc[1] += w * hi16(hv.x);
        acc[2] += w * lo16(hv.y); acc[3] += w * hi16(hv.y);
        acc[4] += w * lo16(hv.z); acc[5] += w * hi16(hv.z);
        acc[6] += w * lo16(hv.w); acc[7] += w * hi16(hv.w);
        j = j2;
    }
    *(float4*)&part[grp][lane * 8]     = make_float4(acc[0], acc[1], acc[2], acc[3]);
    *(float4*)&part[grp][lane * 8 + 4] = make_float4(acc[4], acc[5], acc[6], acc[7]);
    __syncthreads();
    const int c = tid * 2;
    float v0 = part[0][c] + part[1][c] + part[2][c] + part[3][c];
    float v1 = part[0][c + 1] + part[1][c + 1] + part[2][c + 1] + part[3][c + 1];
    float iv = invp[(n << 2) + (c >> 7)];
    v0 *= iv; v1 *= iv;
    unsigned int o = (unsigned)f2b(v0) | ((unsigned)f2b(v1) << 16);
    *(unsigned int*)&aggb[(size_t)n * DINC + c] = o;
}

// ---------------- BatchNorm (bf16 agg) ----------------
__global__ __launch_bounds__(256) void k_bn_stats(const unsigned short* __restrict__ aggb,
                                                  float* __restrict__ stats) {
    int tid = threadIdx.x;
    int row0 = blockIdx.x * 64;
    int c0 = tid * 2;
    float s0 = 0, q0 = 0, s1 = 0, q1 = 0;
    for (int r = row0; r < row0 + 64; ++r) {
        unsigned int hv = *(const unsigned int*)&aggb[(size_t)r * DINC + c0];
        float v0 = lo16(hv), v1 = hi16(hv);
        s0 += v0; q0 += v0 * v0;
        s1 += v1; q1 += v1 * v1;
    }
    atomicAdd(&stats[c0], s0);
    atomicAdd(&stats[c0 + 1], s1);
    atomicAdd(&stats[DINC + c0], q0);
    atomicAdd(&stats[DINC + c0 + 1], q1);
}

__global__ __launch_bounds__(512) void k_bn_fin(const float* __restrict__ stats,
                                                const float* __restrict__ g,
                                                const float* __restrict__ be,
                                                float* __restrict__ ab) {
    int c = threadIdx.x;
    float mu = stats[c] * (1.f / N_NODES);
    float var = stats[DINC + c] * (1.f / N_NODES) - mu * mu;
    float rstd = rsqrtf(var + BN_EPS);
    float A = g[c] * rstd;
    ab[c] = A;
    ab[DINC + c] = be[c] - mu * A;
}

__global__ __launch_bounds__(256) void k_bn_act(const unsigned short* __restrict__ aggb,
                                                const float* __restrict__ ab,
                                                unsigned short* __restrict__ curb,
                                                int res) {
    size_t idx = (size_t)blockIdx.x * 256 + threadIdx.x;   // < N*128
    int c4 = ((int)(idx & 127)) * 4;
    ushort4 v = *(const ushort4*)&aggb[idx * 4];
    float4 A = *(const float4*)(ab + c4);
    float4 B = *(const float4*)(ab + DINC + c4);
    float x0 = lrelu(b2f(v.x) * A.x + B.x);
    float x1 = lrelu(b2f(v.y) * A.y + B.y);
    float x2 = lrelu(b2f(v.z) * A.z + B.z);
    float x3 = lrelu(b2f(v.w) * A.w + B.w);
    if (res) {
        ushort4 r = *(const ushort4*)&curb[idx * 4];
        x0 += b2f(r.x); x1 += b2f(r.y); x2 += b2f(r.z); x3 += b2f(r.w);
    }
    ushort4 o;
    o.x = f2b(x0); o.y = f2b(x1); o.z = f2b(x2); o.w = f2b(x3);
    *(ushort4*)&curb[idx * 4] = o;
}

// ---------------- epilogue ----------------
// Gf layout: [M][256], cols 0..127 = G, 128..255 = F
__global__ __launch_bounds__(256) void k_scores(float* __restrict__ Gf,
                                                const float* __restrict__ bg1,
                                                const float* __restrict__ Wg2,
                                                const float* __restrict__ bg2,
                                                const float* __restrict__ bf1,
                                                float* __restrict__ scores) {
    int n = blockIdx.x * 4 + (threadIdx.x >> 6);
    int lane = threadIdx.x & 63;
    float acc = 0.f;
#pragma unroll
    for (int rep = 0; rep < 2; ++rep) {
        int j = lane + rep * 64;
        float t = tanhf(Gf[(size_t)n * 256 + j] + bg1[j]);
        acc += t * Wg2[j];
        float f = Gf[(size_t)n * 256 + 128 + j] + bf1[j];
        Gf[(size_t)n * 256 + 128 + j] = fmaxf(f, 0.f);
    }
#pragma unroll
    for (int off = 32; off; off >>= 1) acc += __shfl_xor(acc, off);
    if (lane == 0) scores[n] = acc + bg2[0];
}

__global__ __launch_bounds__(1024) void k_softmax(const float* __restrict__ scores, float* __restrict__ sm) {
    __shared__ float red[16];
    int tid = threadIdx.x, lane = tid & 63, wv = tid >> 6;
    float m = -1e30f;
    for (int i = tid; i < N_NODES; i += 1024) m = fmaxf(m, scores[i]);
#pragma unroll
    for (int off = 32; off; off >>= 1) m = fmaxf(m, __shfl_xor(m, off));
    if (lane == 0) red[wv] = m;
    __syncthreads();
    float mall = red[0];
    for (int i = 1; i < 16; ++i) mall = fmaxf(mall, red[i]);
    __syncthreads();
    float s = 0.f;
    for (int i = tid; i < N_NODES; i += 1024) s += expf(scores[i] - mall);
#pragma unroll
    for (int off = 32; off; off >>= 1) s += __shfl_xor(s, off);
    if (lane == 0) red[wv] = s;
    __syncthreads();
    if (tid == 0) {
        float tot = 0.f;
        for (int i = 0; i < 16; ++i) tot += red[i];
        sm[0] = mall; sm[1] = tot;
    }
}

__global__ __launch_bounds__(640) void k_vpool(const float* __restrict__ Gf,
                                               const unsigned short* __restrict__ hb,
                                               const float* __restrict__ scores,
                                               const float* __restrict__ sm,
                                               float* __restrict__ v,
                                               float* __restrict__ pooled) {
    int tid = threadIdx.x;
    int row0 = blockIdx.x * 64;
    float mall = sm[0];
    float invS = 1.f / sm[1];
    if (tid < 128) {
        float acc = 0.f;
        for (int r = row0; r < row0 + 64; ++r) {
            float w = expf(scores[r] - mall) * invS;
            acc += w * Gf[(size_t)r * 256 + 128 + tid];
        }
        atomicAdd(&v[tid], acc);
    } else {
        int c = tid - 128;
        float acc = 0.f;
        for (int r = row0; r < row0 + 64; ++r) acc += b2f(hb[(size_t)r * DINC + c]);
        atomicAdd(&pooled[c], acc * (1.f / N_NODES));
    }
}

__global__ __launch_bounds__(128) void k_final(const float* __restrict__ v,
                                               const float* __restrict__ pooled,
                                               const float* __restrict__ Wf2,
                                               const float* __restrict__ bf2,
                                               const float* __restrict__ Wp,
                                               const float* __restrict__ bp,
                                               float* __restrict__ out) {
    __shared__ float sg[128];
    int o = threadIdx.x;
    float g = bf2[o];
    for (int k = 0; k < 128; ++k) g += v[k] * Wf2[k * 128 + o];
    sg[o] = g;
    __syncthreads();
    float acc = bp[o];
    for (int c = 0; c < 128; ++c) acc += sg[c] * Wp[c * 128 + o];
    for (int j = 0; j < 512; ++j) acc += pooled[j] * Wp[(128 + j) * 128 + o];
    out[o] = acc;
}

// ---------------- host launch ----------------
extern "C" void kernel_launch(void* const* d_in, const int* in_sizes, int n_in,
                              void* d_out, int out_size, void* d_ws, size_t ws_size,
                              hipStream_t stream) {
    const float* x  = (const float*)d_in[0];
    const int*   ei = (const int*)d_in[1];
    const float* Wg1 = (const float*)d_in[20];
    const float* bg1 = (const float*)d_in[21];
    const float* Wg2 = (const float*)d_in[22];
    const float* bg2 = (const float*)d_in[23];
    const float* Wf1 = (const float*)d_in[24];
    const float* bf1 = (const float*)d_in[25];
    const float* Wf2 = (const float*)d_in[26];
    const float* bf2 = (const float*)d_in[27];
    const float* Wp  = (const float*)d_in[28];
    const float* bp  = (const float*)d_in[29];
    float* out = (float*)d_out;

    char* base = (char*)d_ws;
    size_t off = 0;
    auto take = [&](size_t nbytes) -> char* {
        char* p = base + off;
        off += (nbytes + 255) & ~(size_t)255;
        return p;
    };
    unsigned short* hb   = (unsigned short*)take((size_t)M_PAD * DINC * 2);  // GEMM out (bf16 h)
    unsigned short* curb = (unsigned short*)take((size_t)M_PAD * DINC * 2);  // activations bf16
    unsigned short* xb   = (unsigned short*)take((size_t)M_PAD * DINC * 2);  // x bf16
    unsigned short* aggb = (unsigned short*)take((size_t)M_PAD * DINC * 2);  // bf16 agg
    float* Gf    = (float*)take((size_t)M_PAD * 256 * 4);                    // [M,256] G|F
    float* es    = (float*)take((size_t)N_NODES * NHEAD * 4);
    float* ed    = (float*)take((size_t)N_NODES * NHEAD * 4);
    float* wbuf  = (float*)take((size_t)ETOT * NHEAD * 4);
    float* invp  = (float*)take((size_t)N_NODES * NHEAD * 4);
    int*   rowptr= (int*)take((size_t)(N_NODES + 1) * 4);
    int*   cnt   = (int*)take((size_t)N_NODES * 4);
    int*   csr   = (int*)take((size_t)ETOT * 4);
    int*   bsum  = (int*)take(625 * 4);
    int*   bpref = (int*)take(625 * 4);
    float* stats = (float*)take(DINC * 2 * 4);
    float* ab    = (float*)take(DINC * 2 * 4);
    float* sm    = (float*)take(2 * 4);
    float* vbuf  = (float*)take(128 * 4);
    float* pooled= (float*)take(DINC * 4);
    unsigned short* Wt1  = (unsigned short*)take((size_t)DINC * DINC * 2);
    unsigned short* Wt2  = (unsigned short*)take((size_t)DINC * DINC * 2);
    unsigned short* Wt3  = (unsigned short*)take((size_t)DINC * DINC * 2);
    unsigned short* Wct  = (unsigned short*)take((size_t)256 * DINC * 2);    // Wg1t|Wf1t

    // conversions
    k_cvtx<<<(N_NODES * DINC / 8) / 256, 256, 0, stream>>>((const float4*)x, (uint4*)xb);
    hipMemsetAsync(xb + (size_t)N_NODES * DINC, 0, (size_t)(M_PAD - N_NODES) * DINC * 2, stream);
    hipMemsetAsync(curb + (size_t)N_NODES * DINC, 0, (size_t)(M_PAD - N_NODES) * DINC * 2, stream);
    k_cvtw<<<DINC * DINC / 256, 256, 0, stream>>>((const float*)d_in[2],  Wt1, DINC, DINC);
    k_cvtw<<<DINC * DINC / 256, 256, 0, stream>>>((const float*)d_in[8],  Wt2, DINC, DINC);
    k_cvtw<<<DINC * DINC / 256, 256, 0, stream>>>((const float*)d_in[14], Wt3, DINC, DINC);
    k_cvtw<<<DINC * 128 / 256, 256, 0, stream>>>(Wg1, Wct, DINC, 128);
    k_cvtw<<<DINC * 128 / 256, 256, 0, stream>>>(Wf1, Wct + (size_t)128 * DINC, DINC, 128);

    // CSR build
    hipMemsetAsync(cnt, 0, N_NODES * 4, stream);
    k_degree<<<(ETOT + 255) / 256, 256, 0, stream>>>(ei, cnt);
    k_scan1<<<625, 64, 0, stream>>>(cnt, bsum);
    k_scan2<<<1, 1024, 0, stream>>>(bsum, bpref, rowptr);
    k_scan3<<<625, 64, 0, stream>>>(cnt, bpref, rowptr);
    hipMemsetAsync(cnt, 0, N_NODES * 4, stream);
    k_fill<<<(ETOT + 255) / 256, 256, 0, stream>>>(ei, rowptr, cnt, csr);

    const unsigned short* Wts[3] = {Wt1, Wt2, Wt3};
    const unsigned short* in = xb;
    for (int l = 0; l < 3; ++l) {
        const float* as_ = (const float*)d_in[2 + l * 6 + 1];
        const float* ad_ = (const float*)d_in[2 + l * 6 + 2];
        const float* g   = (const float*)d_in[2 + l * 6 + 4];
        const float* be  = (const float*)d_in[2 + l * 6 + 5];

        k_gemm_mfma<1><<<(M_PAD / 128) * (DINC / 128), 256, 0, stream>>>(in, Wts[l], hb, DINC, DINC, DINC / 128);
        k_esed<<<N_NODES / 4, 256, 0, stream>>>(hb, as_, ad_, es, ed);
        k_wts<<<N_NODES / 4, 256, 0, stream>>>((const float4*)es, (const float4*)ed, rowptr, csr,
                                               (float4*)wbuf, (float4*)invp);
        k_agg<<<N_NODES, 256, 0, stream>>>(hb, rowptr, csr, wbuf, invp, aggb);
        hipMemsetAsync(stats, 0, DINC * 2 * 4, stream);
        k_bn_stats<<<N_NODES / 64, 256, 0, stream>>>(aggb, stats);
        k_bn_fin<<<1, 512, 0, stream>>>(stats, g, be, ab);
        k_bn_act<<<(N_NODES * (DINC / 4)) / 256, 256, 0, stream>>>(aggb, ab, curb, l > 0 ? 1 : 0);
        in = curb;
    }

    // combined epilogue GEMM: [M,512] @ [512,256] -> Gf
    k_gemm_mfma<0><<<(M_PAD / 128) * 2, 256, 0, stream>>>(curb, Wct, Gf, 256, DINC, 2);

    float* scores = out + 128;
    k_scores<<<N_NODES / 4, 256, 0, stream>>>(Gf, bg1, Wg2, bg2, bf1, scores);
    k_softmax<<<1, 1024, 0, stream>>>(scores, sm);
    hipMemsetAsync(vbuf, 0, 128 * 4, stream);
    hipMemsetAsync(pooled, 0, DINC * 4, stream);
    k_vpool<<<N_NODES / 64, 640, 0, stream>>>(Gf, curb, scores, sm, vbuf, pooled);
    k_final<<<1, 128, 0, stream>>>(vbuf, pooled, Wf2, bf2, Wp, bp, out);
}